// Round 1
// baseline (377.751 us; speedup 1.0000x reference)
//
#include <hip/hip_runtime.h>
#include <cstdint>
#include <cstddef>

// Problem constants
constexpr int Bc = 4;
constexpr int Tc = 4096;
constexpr int Cc = 1024;
constexpr int Hc = 16;
constexpr int Dc = 64;
constexpr int Mc = Bc * Tc;        // 16384 rows
constexpr int N1c = 3 * Cc;        // 3072
constexpr int Kc = Cc;             // 1024

typedef __bf16 bf16x8 __attribute__((ext_vector_type(8)));
typedef float  f32x4  __attribute__((ext_vector_type(4)));
typedef __attribute__((address_space(1))) uint32_t gu32;
typedef __attribute__((address_space(3))) uint32_t lu32;

__device__ __forceinline__ float bf2f(unsigned short u) {
    return __uint_as_float(((unsigned)u) << 16);
}
__device__ __forceinline__ unsigned short f2bf(float f) {
    unsigned u = __float_as_uint(f);
    u += 0x7FFF + ((u >> 16) & 1);   // round-to-nearest-even (finite values)
    return (unsigned short)(u >> 16);
}

__device__ __forceinline__ void load_lds16(const void* g, void* l) {
    // wave-uniform LDS base + lane*16; per-lane global address
    __builtin_amdgcn_global_load_lds((gu32*)(uintptr_t)g, (lu32*)(uintptr_t)l, 16, 0, 0);
}

// ---------------- fp32 -> bf16 convert (vectorized) ----------------
__global__ void convert_bf16_kernel(const float* __restrict__ in,
                                    unsigned short* __restrict__ out, int n) {
    int i = (blockIdx.x * blockDim.x + threadIdx.x) * 4;
    if (i >= n) return;
    float4 v = *(const float4*)(in + i);
    *(ushort4*)(out + i) = make_ushort4(f2bf(v.x), f2bf(v.y), f2bf(v.z), f2bf(v.w));
}

// ---------------- transpose + convert: W[K][N] fp32 -> Wt[N][K] bf16 ----------------
__global__ void transpose_convert_kernel(const float* __restrict__ W,
                                         unsigned short* __restrict__ Wt,
                                         int K, int N) {
    __shared__ float tile[32][33];
    int n0 = blockIdx.x * 32, k0 = blockIdx.y * 32;
    for (int i = threadIdx.y; i < 32; i += 8)
        tile[i][threadIdx.x] = W[(size_t)(k0 + i) * N + n0 + threadIdx.x];
    __syncthreads();
    for (int i = threadIdx.y; i < 32; i += 8)
        Wt[(size_t)(n0 + i) * K + k0 + threadIdx.x] = f2bf(tile[threadIdx.x][i]);
}

// ---------------- bf16 MFMA GEMM: C[M][N] = A[M][K] * Bt[N][K]^T + bias[N] ----------------
// m97 structure: 128x128 tile, 4 waves, each wave 64x64 = 4x4 MFMA(16x16x32),
// global_load_lds width-16 staging, 2-barrier K-loop.
template <bool OUT_BF16>
__global__ __launch_bounds__(256) void gemm_bt_kernel(
    const unsigned short* __restrict__ A,
    const unsigned short* __restrict__ Bt,
    const float* __restrict__ bias,
    void* __restrict__ Cout,
    int M, int N, int K) {
    __shared__ unsigned short sA[128 * 32];
    __shared__ unsigned short sB[128 * 32];
    const int tid  = threadIdx.x;
    const int w    = tid >> 6;
    const int lane = tid & 63;
    const int m0 = blockIdx.y * 128;
    const int n0 = blockIdx.x * 128;

    // staging: each wave loads 32 rows of A-tile and 32 rows of B-tile
    const int lr = lane >> 2;          // 0..15 row within a 16-row chunk
    const int lc = (lane & 3) * 8;     // 8-elem column chunk
    const unsigned short* gA0 = A  + (size_t)(m0 + w * 32      + lr) * K + lc;
    const unsigned short* gA1 = A  + (size_t)(m0 + w * 32 + 16 + lr) * K + lc;
    const unsigned short* gB0 = Bt + (size_t)(n0 + w * 32      + lr) * K + lc;
    const unsigned short* gB1 = Bt + (size_t)(n0 + w * 32 + 16 + lr) * K + lc;
    unsigned short* lA0 = sA + (w * 32     ) * 32;
    unsigned short* lA1 = sA + (w * 32 + 16) * 32;
    unsigned short* lB0 = sB + (w * 32     ) * 32;
    unsigned short* lB1 = sB + (w * 32 + 16) * 32;

    // compute: wave quadrant (64x64), fragments
    const int wm = (w >> 1) * 64;
    const int wn = (w & 1) * 64;
    const int fr = lane & 15;          // A row / B col within 16x16 tile
    const int fq = lane >> 4;          // quad: k = fq*8 + j
    const unsigned short* aP = sA + (wm + fr) * 32 + fq * 8;
    const unsigned short* bP = sB + (wn + fr) * 32 + fq * 8;

    const f32x4 zero4 = {0.f, 0.f, 0.f, 0.f};
    f32x4 acc[4][4];
    for (int i = 0; i < 4; ++i)
        for (int j = 0; j < 4; ++j) acc[i][j] = zero4;

    for (int kt = 0; kt < K; kt += 32) {
        load_lds16(gA0, lA0);
        load_lds16(gA1, lA1);
        load_lds16(gB0, lB0);
        load_lds16(gB1, lB1);
        gA0 += 32; gA1 += 32; gB0 += 32; gB1 += 32;
        __syncthreads();   // drains vmcnt (global_load_lds) + aligns waves

        bf16x8 af[4], bfr[4];
        #pragma unroll
        for (int mi = 0; mi < 4; ++mi) af[mi]  = *(const bf16x8*)(aP + mi * 16 * 32);
        #pragma unroll
        for (int ni = 0; ni < 4; ++ni) bfr[ni] = *(const bf16x8*)(bP + ni * 16 * 32);
        #pragma unroll
        for (int mi = 0; mi < 4; ++mi)
            #pragma unroll
            for (int ni = 0; ni < 4; ++ni)
                acc[mi][ni] = __builtin_amdgcn_mfma_f32_16x16x32_bf16(
                    af[mi], bfr[ni], acc[mi][ni], 0, 0, 0);
        __syncthreads();   // LDS consumed before next staging overwrites
    }

    // epilogue: D row = (lane>>4)*4 + reg, col = lane&15 (verified m89/m91 layout)
    #pragma unroll
    for (int mi = 0; mi < 4; ++mi) {
        #pragma unroll
        for (int ni = 0; ni < 4; ++ni) {
            int row = m0 + wm + mi * 16 + fq * 4;
            int col = n0 + wn + ni * 16 + fr;
            float bb = bias[col];
            #pragma unroll
            for (int r = 0; r < 4; ++r) {
                float v = acc[mi][ni][r] + bb;
                if (OUT_BF16)
                    ((unsigned short*)Cout)[(size_t)(row + r) * N + col] = f2bf(v);
                else
                    ((float*)Cout)[(size_t)(row + r) * N + col] = v;
            }
        }
    }
}

// ---------------- per-token head-axis attention ----------------
// One wave per token. qkv row = [q(16x64) | k(16x64) | v(16x64)] bf16.
// scores s[h][g] = q[h]·k[g]/8, softmax over g, out[h][d] = sum_g p[h][g] v[g][d].
// LDS per wave: q/k/v padded [16][68] fp32 (+4 pad kills same-bank serialization),
// scores [16][17]. 3536 floats/wave.
__global__ __launch_bounds__(256) void attn_kernel(
    const unsigned short* __restrict__ qkv,
    unsigned short* __restrict__ att) {
    __shared__ float smem[4 * 3536];
    const int w    = threadIdx.x >> 6;
    const int lane = threadIdx.x & 63;
    const int row  = blockIdx.x * 4 + w;
    float* base = smem + w * 3536;

    // cooperative load: 3072 bf16, 48/lane via 16B chunks
    const unsigned short* src = qkv + (size_t)row * 3072;
    #pragma unroll
    for (int it = 0; it < 6; ++it) {
        int e0 = lane * 48 + it * 8;               // byte offset lane*96+it*16: 16B aligned
        uint4 raw = *(const uint4*)(src + e0);
        unsigned short us[8];
        *(uint4*)us = raw;
        #pragma unroll
        for (int jj = 0; jj < 8; ++jj) {
            int e = e0 + jj;
            int seg = e >> 10;                     // 0=q 1=k 2=v
            int i = e & 1023;
            base[seg * 1088 + (i >> 6) * 68 + (i & 63)] = bf2f(us[jj]);
        }
    }
    __syncthreads();

    const int lh = lane >> 2;   // head 0..15
    const int ls = lane & 3;

    // each lane: 4 scores for g = ls + 4j
    float sc[4] = {0.f, 0.f, 0.f, 0.f};
    const float* qrow  = base + lh * 68;
    const float* kbase = base + 1088;
    for (int d = 0; d < 64; ++d) {
        float qv = qrow[d];
        #pragma unroll
        for (int j = 0; j < 4; ++j) sc[j] += qv * kbase[(ls + 4 * j) * 68 + d];
    }
    #pragma unroll
    for (int j = 0; j < 4; ++j) sc[j] *= 0.125f;   // 1/sqrt(64)

    // softmax over 16 g's: reduce across the 4-lane group (xor 1,2)
    float mx = fmaxf(fmaxf(sc[0], sc[1]), fmaxf(sc[2], sc[3]));
    mx = fmaxf(mx, __shfl_xor(mx, 1));
    mx = fmaxf(mx, __shfl_xor(mx, 2));
    float ex[4]; float sum = 0.f;
    #pragma unroll
    for (int j = 0; j < 4; ++j) { ex[j] = __expf(sc[j] - mx); sum += ex[j]; }
    sum += __shfl_xor(sum, 1);
    sum += __shfl_xor(sum, 2);
    float inv = 1.f / sum;
    float* ss = base + 3264;
    #pragma unroll
    for (int j = 0; j < 4; ++j) ss[lh * 17 + ls + 4 * j] = ex[j] * inv;
    __syncthreads();

    // out[h][d] for d in [ls*16, ls*16+16)
    const int d0 = ls * 16;
    float o[16];
    #pragma unroll
    for (int dd = 0; dd < 16; ++dd) o[dd] = 0.f;
    const float* vbase = base + 2176;
    const float* ssrow = base + 3264 + lh * 17;
    for (int g = 0; g < 16; ++g) {
        float pg = ssrow[g];
        const float* vrow = vbase + g * 68 + d0;
        #pragma unroll
        for (int dd = 0; dd < 16; ++dd) o[dd] += pg * vrow[dd];
    }
    unsigned short outv[16];
    #pragma unroll
    for (int dd = 0; dd < 16; ++dd) outv[dd] = f2bf(o[dd]);
    unsigned short* dst = att + (size_t)row * 1024 + lh * 64 + d0;  // 32B-aligned
    *(uint4*)(dst)     = *(uint4*)(outv);
    *(uint4*)(dst + 8) = *(uint4*)(outv + 8);
}

extern "C" void kernel_launch(void* const* d_in, const int* in_sizes, int n_in,
                              void* d_out, int out_size, void* d_ws, size_t ws_size,
                              hipStream_t stream) {
    const float* x    = (const float*)d_in[0];
    const float* Wqkv = (const float*)d_in[1];
    const float* bqkv = (const float*)d_in[2];
    const float* Wout = (const float*)d_in[3];
    const float* bout = (const float*)d_in[4];
    float* out = (float*)d_out;

    // workspace layout (bytes): xb 32M | Wqkv_t 6M | Wout_t 2M | qkv 96M  = ~136 MB
    // att-out reuses xb (dead after GEMM1).
    char* ws = (char*)d_ws;
    unsigned short* xb   = (unsigned short*)ws;                 ws += (size_t)Mc * Kc * 2;
    unsigned short* Wqkt = (unsigned short*)ws;                 ws += (size_t)N1c * Kc * 2;
    unsigned short* Wot  = (unsigned short*)ws;                 ws += (size_t)Cc * Kc * 2;
    unsigned short* qkv  = (unsigned short*)ws;
    unsigned short* att  = xb;   // alias: xb dead after GEMM1

    // 1) x -> bf16
    convert_bf16_kernel<<<(Mc * Kc) / 4 / 256, 256, 0, stream>>>(x, xb, Mc * Kc);
    // 2) weights -> transposed bf16 [N][K]
    transpose_convert_kernel<<<dim3(N1c / 32, Kc / 32), dim3(32, 8), 0, stream>>>(Wqkv, Wqkt, Kc, N1c);
    transpose_convert_kernel<<<dim3(Cc / 32, Kc / 32), dim3(32, 8), 0, stream>>>(Wout, Wot, Kc, Cc);
    // 3) qkv = x @ W_qkv + b_qkv   (bf16 out)
    gemm_bt_kernel<true><<<dim3(N1c / 128, Mc / 128), 256, 0, stream>>>(xb, Wqkt, bqkv, qkv, Mc, N1c, Kc);
    // 4) head-axis attention per token
    attn_kernel<<<Mc / 4, 256, 0, stream>>>(qkv, att);
    // 5) out = att @ W_out + b_out (fp32 out)
    gemm_bt_kernel<false><<<dim3(Cc / 128, Mc / 128), 256, 0, stream>>>(att, Wot, bout, out, Mc, Cc, Kc);
}

// Round 2
// 358.285 us; speedup vs baseline: 1.0543x; 1.0543x over previous
//
#include <hip/hip_runtime.h>
#include <cstdint>
#include <cstddef>

// Problem constants
constexpr int Bc = 4;
constexpr int Tc = 4096;
constexpr int Cc = 1024;
constexpr int Hc = 16;
constexpr int Dc = 64;
constexpr int Mc = Bc * Tc;        // 16384 rows
constexpr int N1c = 3 * Cc;        // 3072
constexpr int Kc = Cc;             // 1024

typedef __bf16 bf16x8 __attribute__((ext_vector_type(8)));
typedef float  f32x4  __attribute__((ext_vector_type(4)));
typedef __attribute__((address_space(1))) uint32_t gu32;
typedef __attribute__((address_space(3))) uint32_t lu32;

__device__ __forceinline__ float bf2f(unsigned short u) {
    return __uint_as_float(((unsigned)u) << 16);
}
__device__ __forceinline__ unsigned short f2bf(float f) {
    unsigned u = __float_as_uint(f);
    u += 0x7FFF + ((u >> 16) & 1);   // round-to-nearest-even (finite values)
    return (unsigned short)(u >> 16);
}

__device__ __forceinline__ void load_lds16(const void* g, void* l) {
    // wave-uniform LDS base + lane*16; per-lane global address
    __builtin_amdgcn_global_load_lds((gu32*)(uintptr_t)g, (lu32*)(uintptr_t)l, 16, 0, 0);
}

// ---------------- fp32 -> bf16 convert (vectorized) ----------------
__global__ void convert_bf16_kernel(const float* __restrict__ in,
                                    unsigned short* __restrict__ out, int n) {
    int i = (blockIdx.x * blockDim.x + threadIdx.x) * 4;
    if (i >= n) return;
    float4 v = *(const float4*)(in + i);
    *(ushort4*)(out + i) = make_ushort4(f2bf(v.x), f2bf(v.y), f2bf(v.z), f2bf(v.w));
}

// ---------------- transpose + convert: W[K][N] fp32 -> Wt[N][K] bf16 ----------------
__global__ void transpose_convert_kernel(const float* __restrict__ W,
                                         unsigned short* __restrict__ Wt,
                                         int K, int N) {
    __shared__ float tile[32][33];
    int n0 = blockIdx.x * 32, k0 = blockIdx.y * 32;
    for (int i = threadIdx.y; i < 32; i += 8)
        tile[i][threadIdx.x] = W[(size_t)(k0 + i) * N + n0 + threadIdx.x];
    __syncthreads();
    for (int i = threadIdx.y; i < 32; i += 8)
        Wt[(size_t)(n0 + i) * K + k0 + threadIdx.x] = f2bf(tile[threadIdx.x][i]);
}

// ---------------- bf16 MFMA GEMM: C[M][N] = A[M][K] * Bt[N][K]^T + bias[N] ----------------
// m97 structure: 128x128 tile, 4 waves, each wave 64x64 = 4x4 MFMA(16x16x32),
// global_load_lds width-16 staging, 2-barrier K-loop. (Unchanged from R1 — passing.)
template <bool OUT_BF16>
__global__ __launch_bounds__(256) void gemm_bt_kernel(
    const unsigned short* __restrict__ A,
    const unsigned short* __restrict__ Bt,
    const float* __restrict__ bias,
    void* __restrict__ Cout,
    int M, int N, int K) {
    __shared__ unsigned short sA[128 * 32];
    __shared__ unsigned short sB[128 * 32];
    const int tid  = threadIdx.x;
    const int w    = tid >> 6;
    const int lane = tid & 63;
    const int m0 = blockIdx.y * 128;
    const int n0 = blockIdx.x * 128;

    const int lr = lane >> 2;          // 0..15 row within a 16-row chunk
    const int lc = (lane & 3) * 8;     // 8-elem column chunk
    const unsigned short* gA0 = A  + (size_t)(m0 + w * 32      + lr) * K + lc;
    const unsigned short* gA1 = A  + (size_t)(m0 + w * 32 + 16 + lr) * K + lc;
    const unsigned short* gB0 = Bt + (size_t)(n0 + w * 32      + lr) * K + lc;
    const unsigned short* gB1 = Bt + (size_t)(n0 + w * 32 + 16 + lr) * K + lc;
    unsigned short* lA0 = sA + (w * 32     ) * 32;
    unsigned short* lA1 = sA + (w * 32 + 16) * 32;
    unsigned short* lB0 = sB + (w * 32     ) * 32;
    unsigned short* lB1 = sB + (w * 32 + 16) * 32;

    const int wm = (w >> 1) * 64;
    const int wn = (w & 1) * 64;
    const int fr = lane & 15;
    const int fq = lane >> 4;
    const unsigned short* aP = sA + (wm + fr) * 32 + fq * 8;
    const unsigned short* bP = sB + (wn + fr) * 32 + fq * 8;

    const f32x4 zero4 = {0.f, 0.f, 0.f, 0.f};
    f32x4 acc[4][4];
    for (int i = 0; i < 4; ++i)
        for (int j = 0; j < 4; ++j) acc[i][j] = zero4;

    for (int kt = 0; kt < K; kt += 32) {
        load_lds16(gA0, lA0);
        load_lds16(gA1, lA1);
        load_lds16(gB0, lB0);
        load_lds16(gB1, lB1);
        gA0 += 32; gA1 += 32; gB0 += 32; gB1 += 32;
        __syncthreads();

        bf16x8 af[4], bfr[4];
        #pragma unroll
        for (int mi = 0; mi < 4; ++mi) af[mi]  = *(const bf16x8*)(aP + mi * 16 * 32);
        #pragma unroll
        for (int ni = 0; ni < 4; ++ni) bfr[ni] = *(const bf16x8*)(bP + ni * 16 * 32);
        #pragma unroll
        for (int mi = 0; mi < 4; ++mi)
            #pragma unroll
            for (int ni = 0; ni < 4; ++ni)
                acc[mi][ni] = __builtin_amdgcn_mfma_f32_16x16x32_bf16(
                    af[mi], bfr[ni], acc[mi][ni], 0, 0, 0);
        __syncthreads();
    }

    #pragma unroll
    for (int mi = 0; mi < 4; ++mi) {
        #pragma unroll
        for (int ni = 0; ni < 4; ++ni) {
            int row = m0 + wm + mi * 16 + fq * 4;
            int col = n0 + wn + ni * 16 + fr;
            float bb = bias[col];
            #pragma unroll
            for (int r = 0; r < 4; ++r) {
                float v = acc[mi][ni][r] + bb;
                if (OUT_BF16)
                    ((unsigned short*)Cout)[(size_t)(row + r) * N + col] = f2bf(v);
                else
                    ((float*)Cout)[(size_t)(row + r) * N + col] = v;
            }
        }
    }
}

// ---------------- per-token head-axis attention, MFMA version ----------------
// One wave per token. qkv row = [q(16x64) | k(16x64) | v(16x64)] bf16, row-major.
// Scores S = Q K^T / 8 via 2x mfma_f32_16x16x32_bf16 with A=Q-frag, B=K-frag
// loaded DIRECTLY from global (A/B layout: [idx=lane&15][k=quad*8+j]).
// S lands in C-layout: S[h=quad*4+r][g=lane&15]. Softmax over g = shfl_xor 1/2/4/8.
// P -> A-layout via LDS round-trip (fp32 [16][20] padded). PV via 4x mfma with
// K padded 16->32: A-frag zeroed for quads 2,3 (annihilates duplicated B rows).
// V transposed through LDS bf16 [16][72] (stride-72: 2-way conflicts only = free).
__global__ __launch_bounds__(256) void attn_mfma_kernel(
    const unsigned short* __restrict__ qkv,
    unsigned short* __restrict__ att) {
    __shared__ char smem[4 * 3584];
    const int w    = threadIdx.x >> 6;
    const int lane = threadIdx.x & 63;
    const int m    = lane & 15;
    const int q    = lane >> 4;
    const int row  = blockIdx.x * 4 + w;
    unsigned short* sV = (unsigned short*)(smem + w * 3584);        // [16][72] bf16
    float*          sP = (float*)(smem + w * 3584 + 2304);          // [16][20] fp32

    const unsigned short* src = qkv + (size_t)row * 3072;

    // Q/K fragments straight from global (16B loads, A/B-operand layout)
    bf16x8 aq0 = *(const bf16x8*)(src + m * 64 + q * 8);
    bf16x8 aq1 = *(const bf16x8*)(src + m * 64 + 32 + q * 8);
    bf16x8 bk0 = *(const bf16x8*)(src + 1024 + m * 64 + q * 8);
    bf16x8 bk1 = *(const bf16x8*)(src + 1024 + m * 64 + 32 + q * 8);

    // stage V (16x64 bf16, contiguous at +2048) into padded LDS [16][72]
    #pragma unroll
    for (int t = 0; t < 2; ++t) {
        int G = t * 64 + lane;            // granule 0..127 (8 elems each)
        int r = G >> 3, p = G & 7;
        *(uint4*)(sV + r * 72 + p * 8) = *(const uint4*)(src + 2048 + G * 8);
    }

    // scores: S[h][g] = q[h]·k[g]
    f32x4 s = {0.f, 0.f, 0.f, 0.f};
    s = __builtin_amdgcn_mfma_f32_16x16x32_bf16(aq0, bk0, s, 0, 0, 0);
    s = __builtin_amdgcn_mfma_f32_16x16x32_bf16(aq1, bk1, s, 0, 0, 0);

    // softmax over g (= lane&15) per row h=q*4+r; write P to LDS fp32
    #pragma unroll
    for (int r = 0; r < 4; ++r) {
        float t0 = s[r] * 0.125f;         // 1/sqrt(64)
        float mx = t0;
        mx = fmaxf(mx, __shfl_xor(mx, 1));
        mx = fmaxf(mx, __shfl_xor(mx, 2));
        mx = fmaxf(mx, __shfl_xor(mx, 4));
        mx = fmaxf(mx, __shfl_xor(mx, 8));
        float e = __expf(t0 - mx);
        float su = e;
        su += __shfl_xor(su, 1);
        su += __shfl_xor(su, 2);
        su += __shfl_xor(su, 4);
        su += __shfl_xor(su, 8);
        sP[(q * 4 + r) * 20 + m] = e / su;
    }
    __syncthreads();

    // P A-fragment: lane holds P[h=m][g=quad*8+j]; quads 2,3 -> zero (K pad 16->32)
    const float* pr = sP + m * 20 + (q & 1) * 8;
    float4 pf0 = *(const float4*)(pr);
    float4 pf1 = *(const float4*)(pr + 4);
    const bool act = (q < 2);
    union { unsigned short u[8]; bf16x8 b; } pa;
    pa.u[0] = act ? f2bf(pf0.x) : 0;
    pa.u[1] = act ? f2bf(pf0.y) : 0;
    pa.u[2] = act ? f2bf(pf0.z) : 0;
    pa.u[3] = act ? f2bf(pf0.w) : 0;
    pa.u[4] = act ? f2bf(pf1.x) : 0;
    pa.u[5] = act ? f2bf(pf1.y) : 0;
    pa.u[6] = act ? f2bf(pf1.z) : 0;
    pa.u[7] = act ? f2bf(pf1.w) : 0;

    // PV: out[h][d] = sum_g P[h][g] V[g][d], d in 4 chunks of 16
    const unsigned short* vb = sV + (q & 1) * 8 * 72;   // quads 2,3 duplicate 0,1 (A=0 kills them)
    unsigned short* dst = att + (size_t)row * 1024;
    #pragma unroll
    for (int c4 = 0; c4 < 4; ++c4) {
        union { unsigned short u[8]; bf16x8 b; } vf;
        #pragma unroll
        for (int j = 0; j < 8; ++j) vf.u[j] = vb[j * 72 + c4 * 16 + m];
        f32x4 o = {0.f, 0.f, 0.f, 0.f};
        o = __builtin_amdgcn_mfma_f32_16x16x32_bf16(pa.b, vf.b, o, 0, 0, 0);
        #pragma unroll
        for (int r = 0; r < 4; ++r)
            dst[(q * 4 + r) * 64 + c4 * 16 + m] = f2bf(o[r]);
    }
}

extern "C" void kernel_launch(void* const* d_in, const int* in_sizes, int n_in,
                              void* d_out, int out_size, void* d_ws, size_t ws_size,
                              hipStream_t stream) {
    const float* x    = (const float*)d_in[0];
    const float* Wqkv = (const float*)d_in[1];
    const float* bqkv = (const float*)d_in[2];
    const float* Wout = (const float*)d_in[3];
    const float* bout = (const float*)d_in[4];
    float* out = (float*)d_out;

    // workspace layout (bytes): xb 32M | Wqkv_t 6M | Wout_t 2M | qkv 96M  = ~136 MB
    char* ws = (char*)d_ws;
    unsigned short* xb   = (unsigned short*)ws;                 ws += (size_t)Mc * Kc * 2;
    unsigned short* Wqkt = (unsigned short*)ws;                 ws += (size_t)N1c * Kc * 2;
    unsigned short* Wot  = (unsigned short*)ws;                 ws += (size_t)Cc * Kc * 2;
    unsigned short* qkv  = (unsigned short*)ws;
    unsigned short* att  = xb;   // alias: xb dead after GEMM1

    // 1) x -> bf16
    convert_bf16_kernel<<<(Mc * Kc) / 4 / 256, 256, 0, stream>>>(x, xb, Mc * Kc);
    // 2) weights -> transposed bf16 [N][K]
    transpose_convert_kernel<<<dim3(N1c / 32, Kc / 32), dim3(32, 8), 0, stream>>>(Wqkv, Wqkt, Kc, N1c);
    transpose_convert_kernel<<<dim3(Cc / 32, Kc / 32), dim3(32, 8), 0, stream>>>(Wout, Wot, Kc, Cc);
    // 3) qkv = x @ W_qkv + b_qkv   (bf16 out)
    gemm_bt_kernel<true><<<dim3(N1c / 128, Mc / 128), 256, 0, stream>>>(xb, Wqkt, bqkv, qkv, Mc, N1c, Kc);
    // 4) head-axis attention per token (MFMA)
    attn_mfma_kernel<<<Mc / 4, 256, 0, stream>>>(qkv, att);
    // 5) out = att @ W_out + b_out (fp32 out)
    gemm_bt_kernel<false><<<dim3(Cc / 128, Mc / 128), 256, 0, stream>>>(att, Wot, bout, out, Mc, Cc, Kc);
}

// Round 3
// 336.845 us; speedup vs baseline: 1.1214x; 1.0636x over previous
//
#include <hip/hip_runtime.h>
#include <cstdint>
#include <cstddef>

// Problem constants
constexpr int Bc = 4;
constexpr int Tc = 4096;
constexpr int Cc = 1024;
constexpr int Hc = 16;
constexpr int Dc = 64;
constexpr int Mc = Bc * Tc;        // 16384 rows
constexpr int N1c = 3 * Cc;        // 3072
constexpr int Kc = Cc;             // 1024
constexpr int KBc = Kc / 32;       // 32 k-tiles

typedef __bf16 bf16x8 __attribute__((ext_vector_type(8)));
typedef float  f32x4  __attribute__((ext_vector_type(4)));

__device__ __forceinline__ float bf2f(unsigned short u) {
    return __uint_as_float(((unsigned)u) << 16);
}
__device__ __forceinline__ unsigned short f2bf(float f) {
    unsigned u = __float_as_uint(f);
    u += 0x7FFF + ((u >> 16) & 1);   // round-to-nearest-even (finite values)
    return (unsigned short)(u >> 16);
}

// ============ packed-fragment layout ============
// A 16(rows)x32(k) tile = 512 bf16 = 64 lanes x 8 elems.
// lane = fq*16 + fr  (fr = row&15, fq = (k&31)>>3), elem j = k&7.
// tile index (A): (row>>4)*KB + (k>>5);  (B): (col>>4)*KB + (k>>5).
// A wave's fragment load is tile_base + lane*16 bytes -> one coalesced b128.

// ---------------- x fp32 [M][K] -> packed bf16 fragments ----------------
__global__ void convert_x_packed(const float* __restrict__ x,
                                 unsigned short* __restrict__ Ap) {
    const int w = threadIdx.x >> 6, lane = threadIdx.x & 63;
    const int t = blockIdx.x * 4 + w;          // tile id = mb*KB + kb
    const int mb = t >> 5, kb = t & 31;
    const int r = lane >> 2, c = lane & 3;     // read mapping: 16 rows x 4 chunks
    const float* src = x + (size_t)(mb * 16 + r) * Kc + kb * 32 + c * 8;
    float4 f0 = *(const float4*)src;
    float4 f1 = *(const float4*)(src + 4);
    unsigned short u[8];
    u[0] = f2bf(f0.x); u[1] = f2bf(f0.y); u[2] = f2bf(f0.z); u[3] = f2bf(f0.w);
    u[4] = f2bf(f1.x); u[5] = f2bf(f1.y); u[6] = f2bf(f1.z); u[7] = f2bf(f1.w);
    // this lane holds (fr=r, fq=c) -> packed lane' = c*16 + r
    *(uint4*)(Ap + (size_t)t * 512 + (c * 16 + r) * 8) = *(uint4*)u;
}

// ---------------- W fp32 [K][N] -> packed bf16 fragments (transposed) ----------------
__global__ void transpose_convert_packed(const float* __restrict__ W,
                                         unsigned short* __restrict__ Bp,
                                         int K, int N) {
    __shared__ float tile[32][33];
    const int tx = threadIdx.x, ty = threadIdx.y;
    const int n0 = blockIdx.x * 32, k0 = blockIdx.y * 32;
    for (int i = ty; i < 32; i += 8)
        tile[i][tx] = W[(size_t)(k0 + i) * N + n0 + tx];
    __syncthreads();
    // 256 threads emit 2 packed tiles (n-halves), 4 elems (8B) each
    const int t = ty * 32 + tx;
    const int h = t >> 7, rr = t & 127, lane = rr >> 1, half = rr & 1;
    const int fq = lane >> 4, fn = lane & 15;
    unsigned short u[4];
    #pragma unroll
    for (int j = 0; j < 4; ++j)
        u[j] = f2bf(tile[fq * 8 + half * 4 + j][h * 16 + fn]);
    size_t tileIdx = (size_t)((n0 >> 4) + h) * (K >> 5) + (k0 >> 5);
    *(uint2*)(Bp + tileIdx * 512 + lane * 8 + half * 4) = *(uint2*)u;
}

// ---------------- flat (zero-LDS) bf16 MFMA GEMM on packed fragments ----------------
// C[M][N] = A*B^T + bias. 128x128 block, 4 waves, each 64x64 = 4x4 MFMA(16x16x32).
// Per K=32 step: 8 coalesced global b128 fragment loads, 16 MFMA.
// Register double-buffered, no LDS, no barriers.
template <bool OUT_BF16>
__global__ __launch_bounds__(256, 3) void flat_gemm_kernel(
    const unsigned short* __restrict__ Ap,
    const unsigned short* __restrict__ Bp,
    const float* __restrict__ bias,
    void* __restrict__ Cout,
    int M, int N, int K) {
    const int KB = K >> 5;
    const int w    = threadIdx.x >> 6;
    const int lane = threadIdx.x & 63;
    const int m0 = blockIdx.y * 128;
    const int n0 = blockIdx.x * 128;
    const int wm = (w >> 1) * 64;
    const int wn = (w & 1) * 64;

    const unsigned short* Abase = Ap + (size_t)(((m0 + wm) >> 4) * KB) * 512 + lane * 8;
    const unsigned short* Bbase = Bp + (size_t)(((n0 + wn) >> 4) * KB) * 512 + lane * 8;
    const int miStride = KB * 512;   // +1 row-block of 16
    const int kbStride = 512;        // +1 k-block of 32

    const f32x4 zero4 = {0.f, 0.f, 0.f, 0.f};
    f32x4 acc[4][4];
    #pragma unroll
    for (int i = 0; i < 4; ++i)
        #pragma unroll
        for (int j = 0; j < 4; ++j) acc[i][j] = zero4;

    bf16x8 a0[4], b0[4], a1[4], b1[4];
    #pragma unroll
    for (int mi = 0; mi < 4; ++mi) a0[mi] = *(const bf16x8*)(Abase + mi * miStride);
    #pragma unroll
    for (int ni = 0; ni < 4; ++ni) b0[ni] = *(const bf16x8*)(Bbase + ni * miStride);

    #pragma unroll 1
    for (int kb = 0; kb < KB; kb += 2) {
        // prefetch kb+1
        #pragma unroll
        for (int mi = 0; mi < 4; ++mi)
            a1[mi] = *(const bf16x8*)(Abase + mi * miStride + (kb + 1) * kbStride);
        #pragma unroll
        for (int ni = 0; ni < 4; ++ni)
            b1[ni] = *(const bf16x8*)(Bbase + ni * miStride + (kb + 1) * kbStride);
        #pragma unroll
        for (int mi = 0; mi < 4; ++mi)
            #pragma unroll
            for (int ni = 0; ni < 4; ++ni)
                acc[mi][ni] = __builtin_amdgcn_mfma_f32_16x16x32_bf16(
                    a0[mi], b0[ni], acc[mi][ni], 0, 0, 0);
        // prefetch kb+2
        if (kb + 2 < KB) {
            #pragma unroll
            for (int mi = 0; mi < 4; ++mi)
                a0[mi] = *(const bf16x8*)(Abase + mi * miStride + (kb + 2) * kbStride);
            #pragma unroll
            for (int ni = 0; ni < 4; ++ni)
                b0[ni] = *(const bf16x8*)(Bbase + ni * miStride + (kb + 2) * kbStride);
        }
        #pragma unroll
        for (int mi = 0; mi < 4; ++mi)
            #pragma unroll
            for (int ni = 0; ni < 4; ++ni)
                acc[mi][ni] = __builtin_amdgcn_mfma_f32_16x16x32_bf16(
                    a1[mi], b1[ni], acc[mi][ni], 0, 0, 0);
    }

    // epilogue: D row = (lane>>4)*4 + reg, col = lane&15 (verified m89/m91 layout)
    const int fr = lane & 15;
    const int fq = lane >> 4;
    #pragma unroll
    for (int mi = 0; mi < 4; ++mi) {
        #pragma unroll
        for (int ni = 0; ni < 4; ++ni) {
            int row = m0 + wm + mi * 16 + fq * 4;
            int col = n0 + wn + ni * 16 + fr;
            float bb = bias[col];
            #pragma unroll
            for (int r = 0; r < 4; ++r) {
                float v = acc[mi][ni][r] + bb;
                if (OUT_BF16)
                    ((unsigned short*)Cout)[(size_t)(row + r) * N + col] = f2bf(v);
                else
                    ((float*)Cout)[(size_t)(row + r) * N + col] = v;
            }
        }
    }
}

// ---------------- per-token head-axis attention, MFMA version ----------------
// One wave per token; output written directly in packed-fragment layout so it
// feeds flat_gemm as A. (Same scalar-store count as row-major — zero extra cost.)
__global__ __launch_bounds__(256) void attn_mfma_kernel(
    const unsigned short* __restrict__ qkv,
    unsigned short* __restrict__ attP) {
    __shared__ char smem[4 * 3584];
    const int w    = threadIdx.x >> 6;
    const int lane = threadIdx.x & 63;
    const int m    = lane & 15;
    const int q    = lane >> 4;
    const int row  = blockIdx.x * 4 + w;
    unsigned short* sV = (unsigned short*)(smem + w * 3584);        // [16][72] bf16
    float*          sP = (float*)(smem + w * 3584 + 2304);          // [16][20] fp32

    const unsigned short* src = qkv + (size_t)row * 3072;

    // Q/K fragments straight from global (16B loads, A/B-operand layout)
    bf16x8 aq0 = *(const bf16x8*)(src + m * 64 + q * 8);
    bf16x8 aq1 = *(const bf16x8*)(src + m * 64 + 32 + q * 8);
    bf16x8 bk0 = *(const bf16x8*)(src + 1024 + m * 64 + q * 8);
    bf16x8 bk1 = *(const bf16x8*)(src + 1024 + m * 64 + 32 + q * 8);

    // stage V (16x64 bf16) into padded LDS [16][72]
    #pragma unroll
    for (int t = 0; t < 2; ++t) {
        int G = t * 64 + lane;
        int r = G >> 3, p = G & 7;
        *(uint4*)(sV + r * 72 + p * 8) = *(const uint4*)(src + 2048 + G * 8);
    }

    // scores: S[h][g] = q[h]·k[g]
    f32x4 s = {0.f, 0.f, 0.f, 0.f};
    s = __builtin_amdgcn_mfma_f32_16x16x32_bf16(aq0, bk0, s, 0, 0, 0);
    s = __builtin_amdgcn_mfma_f32_16x16x32_bf16(aq1, bk1, s, 0, 0, 0);

    // softmax over g per row h=q*4+r; P -> LDS fp32
    #pragma unroll
    for (int r = 0; r < 4; ++r) {
        float t0 = s[r] * 0.125f;
        float mx = t0;
        mx = fmaxf(mx, __shfl_xor(mx, 1));
        mx = fmaxf(mx, __shfl_xor(mx, 2));
        mx = fmaxf(mx, __shfl_xor(mx, 4));
        mx = fmaxf(mx, __shfl_xor(mx, 8));
        float e = __expf(t0 - mx);
        float su = e;
        su += __shfl_xor(su, 1);
        su += __shfl_xor(su, 2);
        su += __shfl_xor(su, 4);
        su += __shfl_xor(su, 8);
        sP[(q * 4 + r) * 20 + m] = e / su;
    }
    __syncthreads();

    // P A-fragment: lane holds P[h=m][g=quad*8+j]; quads 2,3 -> zero (K pad 16->32)
    const float* pr = sP + m * 20 + (q & 1) * 8;
    float4 pf0 = *(const float4*)(pr);
    float4 pf1 = *(const float4*)(pr + 4);
    const bool act = (q < 2);
    union { unsigned short u[8]; bf16x8 b; } pa;
    pa.u[0] = act ? f2bf(pf0.x) : 0;
    pa.u[1] = act ? f2bf(pf0.y) : 0;
    pa.u[2] = act ? f2bf(pf0.z) : 0;
    pa.u[3] = act ? f2bf(pf0.w) : 0;
    pa.u[4] = act ? f2bf(pf1.x) : 0;
    pa.u[5] = act ? f2bf(pf1.y) : 0;
    pa.u[6] = act ? f2bf(pf1.z) : 0;
    pa.u[7] = act ? f2bf(pf1.w) : 0;

    // PV: out[h][d] = sum_g P[h][g] V[g][d]
    const unsigned short* vb = sV + (q & 1) * 8 * 72;
    const size_t tileBase = (size_t)(row >> 4) * 32 * 512;   // token's m-block row
    const int fr_tok = row & 15;
    #pragma unroll
    for (int c4 = 0; c4 < 4; ++c4) {
        union { unsigned short u[8]; bf16x8 b; } vf;
        #pragma unroll
        for (int j = 0; j < 8; ++j) vf.u[j] = vb[j * 72 + c4 * 16 + m];
        f32x4 o = {0.f, 0.f, 0.f, 0.f};
        o = __builtin_amdgcn_mfma_f32_16x16x32_bf16(pa.b, vf.b, o, 0, 0, 0);
        #pragma unroll
        for (int r = 0; r < 4; ++r) {
            int col = (q * 4 + r) * 64 + c4 * 16 + m;        // within [0,1024)
            size_t off = tileBase + (size_t)(col >> 5) * 512
                       + (((col >> 3) & 3) * 16 + fr_tok) * 8 + (col & 7);
            attP[off] = f2bf(o[r]);
        }
    }
}

extern "C" void kernel_launch(void* const* d_in, const int* in_sizes, int n_in,
                              void* d_out, int out_size, void* d_ws, size_t ws_size,
                              hipStream_t stream) {
    const float* x    = (const float*)d_in[0];
    const float* Wqkv = (const float*)d_in[1];
    const float* bqkv = (const float*)d_in[2];
    const float* Wout = (const float*)d_in[3];
    const float* bout = (const float*)d_in[4];
    float* out = (float*)d_out;

    // workspace: xp 32M | Wqkv_p 6M | Wout_p 2M | qkv 96M = ~136 MB
    char* ws = (char*)d_ws;
    unsigned short* xp   = (unsigned short*)ws;                 ws += (size_t)Mc * Kc * 2;
    unsigned short* Wqkp = (unsigned short*)ws;                 ws += (size_t)N1c * Kc * 2;
    unsigned short* Wop  = (unsigned short*)ws;                 ws += (size_t)Cc * Kc * 2;
    unsigned short* qkv  = (unsigned short*)ws;
    unsigned short* attP = xp;   // alias: xp dead after GEMM1

    // 1) x -> packed bf16 fragments
    convert_x_packed<<<(Mc / 16) * KBc / 4, 256, 0, stream>>>(x, xp);
    // 2) weights -> packed bf16 fragments (transposed)
    transpose_convert_packed<<<dim3(N1c / 32, Kc / 32), dim3(32, 8), 0, stream>>>(Wqkv, Wqkp, Kc, N1c);
    transpose_convert_packed<<<dim3(Cc / 32, Kc / 32), dim3(32, 8), 0, stream>>>(Wout, Wop, Kc, Cc);
    // 3) qkv = x @ W_qkv + b_qkv   (bf16 row-major out)
    flat_gemm_kernel<true><<<dim3(N1c / 128, Mc / 128), 256, 0, stream>>>(xp, Wqkp, bqkv, qkv, Mc, N1c, Kc);
    // 4) head-axis attention per token (MFMA), writes packed-fragment A
    attn_mfma_kernel<<<Mc / 4, 256, 0, stream>>>(qkv, attP);
    // 5) out = att @ W_out + b_out (fp32 row-major out)
    flat_gemm_kernel<false><<<dim3(Cc / 128, Mc / 128), 256, 0, stream>>>(attP, Wop, bout, out, Mc, Cc, Kc);
}

// Round 4
// 332.820 us; speedup vs baseline: 1.1350x; 1.0121x over previous
//
#include <hip/hip_runtime.h>
#include <cstdint>
#include <cstddef>

// Problem constants
constexpr int Bc = 4;
constexpr int Tc = 4096;
constexpr int Cc = 1024;
constexpr int Hc = 16;
constexpr int Dc = 64;
constexpr int Mc = Bc * Tc;        // 16384 rows
constexpr int N1c = 3 * Cc;        // 3072
constexpr int Kc = Cc;             // 1024
constexpr int KBc = Kc / 32;       // 32 k-tiles

typedef __bf16 bf16x8 __attribute__((ext_vector_type(8)));
typedef float  f32x4  __attribute__((ext_vector_type(4)));

__device__ __forceinline__ float bf2f(unsigned short u) {
    return __uint_as_float(((unsigned)u) << 16);
}
__device__ __forceinline__ unsigned short f2bf(float f) {
    unsigned u = __float_as_uint(f);
    u += 0x7FFF + ((u >> 16) & 1);   // round-to-nearest-even (finite values)
    return (unsigned short)(u >> 16);
}

// ============ packed-fragment layout ============
// A 16(rows)x32(k) tile = 512 bf16 = 64 lanes x 8 elems.
// lane = fq*16 + fr  (fr = row&15, fq = (k&31)>>3), elem j = k&7.
// tile index: (row>>4)*KB + (k>>5). Wave fragment load = tile_base + lane*16B.

// ---------------- x fp32 [M][K] -> packed bf16 fragments ----------------
__global__ void convert_x_packed(const float* __restrict__ x,
                                 unsigned short* __restrict__ Ap) {
    const int w = threadIdx.x >> 6, lane = threadIdx.x & 63;
    const int t = blockIdx.x * 4 + w;          // tile id = mb*KB + kb
    const int mb = t >> 5, kb = t & 31;
    const int r = lane >> 2, c = lane & 3;
    const float* src = x + (size_t)(mb * 16 + r) * Kc + kb * 32 + c * 8;
    float4 f0 = *(const float4*)src;
    float4 f1 = *(const float4*)(src + 4);
    unsigned short u[8];
    u[0] = f2bf(f0.x); u[1] = f2bf(f0.y); u[2] = f2bf(f0.z); u[3] = f2bf(f0.w);
    u[4] = f2bf(f1.x); u[5] = f2bf(f1.y); u[6] = f2bf(f1.z); u[7] = f2bf(f1.w);
    *(uint4*)(Ap + (size_t)t * 512 + (c * 16 + r) * 8) = *(uint4*)u;
}

// ---------------- bf16 row-major [M][K] -> packed fragments ----------------
__global__ void repack_bf16_packed(const unsigned short* __restrict__ src,
                                   unsigned short* __restrict__ Ap) {
    const int w = threadIdx.x >> 6, lane = threadIdx.x & 63;
    const int t = blockIdx.x * 4 + w;
    const int mb = t >> 5, kb = t & 31;
    const int r = lane >> 2, c = lane & 3;
    uint4 v = *(const uint4*)(src + (size_t)(mb * 16 + r) * Kc + kb * 32 + c * 8);
    *(uint4*)(Ap + (size_t)t * 512 + (c * 16 + r) * 8) = v;
}

// ---------------- W fp32 [K][N] -> packed bf16 fragments (transposed) ----------------
__global__ void transpose_convert_packed(const float* __restrict__ W,
                                         unsigned short* __restrict__ Bp,
                                         int K, int N) {
    __shared__ float tile[32][33];
    const int tx = threadIdx.x, ty = threadIdx.y;
    const int n0 = blockIdx.x * 32, k0 = blockIdx.y * 32;
    for (int i = ty; i < 32; i += 8)
        tile[i][tx] = W[(size_t)(k0 + i) * N + n0 + tx];
    __syncthreads();
    const int t = ty * 32 + tx;
    const int h = t >> 7, rr = t & 127, lane = rr >> 1, half = rr & 1;
    const int fq = lane >> 4, fn = lane & 15;
    unsigned short u[4];
    #pragma unroll
    for (int j = 0; j < 4; ++j)
        u[j] = f2bf(tile[fq * 8 + half * 4 + j][h * 16 + fn]);
    size_t tileIdx = (size_t)((n0 >> 4) + h) * (K >> 5) + (k0 >> 5);
    *(uint2*)(Bp + tileIdx * 512 + lane * 8 + half * 4) = *(uint2*)u;
}

// ---------------- flat (zero-LDS) bf16 MFMA GEMM on packed fragments ----------------
// 1-D grid with XCD/L2 swizzle: xcd = id%8 owns M-stripe [xcd*MB/8, ...), walks
// 8-row-block chunks across all NB columns (2MB A resident per XCD L2).
template <bool OUT_BF16>
__global__ __launch_bounds__(256, 4) void flat_gemm_kernel(
    const unsigned short* __restrict__ Ap,
    const unsigned short* __restrict__ Bp,
    const float* __restrict__ bias,
    void* __restrict__ Cout,
    int M, int N, int K, int NB) {
    const int KB = K >> 5;
    const int MB = M >> 7;
    // swizzle
    const int id   = blockIdx.x;
    const int xcd  = id & 7;
    const int per  = id >> 3;
    const int MSTR = MB >> 3;            // M-blocks per XCD stripe
    const int byl  = per & 7;            // chunk of 8 M-blocks
    const int bx   = (per >> 3) % NB;
    const int pass = per / (8 * NB);
    const int by   = xcd * MSTR + pass * 8 + byl;

    const int w    = threadIdx.x >> 6;
    const int lane = threadIdx.x & 63;
    const int m0 = by * 128;
    const int n0 = bx * 128;
    const int wm = (w >> 1) * 64;
    const int wn = (w & 1) * 64;

    const unsigned short* Abase = Ap + (size_t)(((m0 + wm) >> 4) * KB) * 512 + lane * 8;
    const unsigned short* Bbase = Bp + (size_t)(((n0 + wn) >> 4) * KB) * 512 + lane * 8;
    const int miStride = KB * 512;
    const int kbStride = 512;

    const f32x4 zero4 = {0.f, 0.f, 0.f, 0.f};
    f32x4 acc[4][4];
    #pragma unroll
    for (int i = 0; i < 4; ++i)
        #pragma unroll
        for (int j = 0; j < 4; ++j) acc[i][j] = zero4;

    bf16x8 a0[4], b0[4], a1[4], b1[4];
    #pragma unroll
    for (int mi = 0; mi < 4; ++mi) a0[mi] = *(const bf16x8*)(Abase + mi * miStride);
    #pragma unroll
    for (int ni = 0; ni < 4; ++ni) b0[ni] = *(const bf16x8*)(Bbase + ni * miStride);

    #pragma unroll 1
    for (int kb = 0; kb < KB; kb += 2) {
        #pragma unroll
        for (int mi = 0; mi < 4; ++mi)
            a1[mi] = *(const bf16x8*)(Abase + mi * miStride + (kb + 1) * kbStride);
        #pragma unroll
        for (int ni = 0; ni < 4; ++ni)
            b1[ni] = *(const bf16x8*)(Bbase + ni * miStride + (kb + 1) * kbStride);
        #pragma unroll
        for (int mi = 0; mi < 4; ++mi)
            #pragma unroll
            for (int ni = 0; ni < 4; ++ni)
                acc[mi][ni] = __builtin_amdgcn_mfma_f32_16x16x32_bf16(
                    a0[mi], b0[ni], acc[mi][ni], 0, 0, 0);
        if (kb + 2 < KB) {
            #pragma unroll
            for (int mi = 0; mi < 4; ++mi)
                a0[mi] = *(const bf16x8*)(Abase + mi * miStride + (kb + 2) * kbStride);
            #pragma unroll
            for (int ni = 0; ni < 4; ++ni)
                b0[ni] = *(const bf16x8*)(Bbase + ni * miStride + (kb + 2) * kbStride);
        }
        #pragma unroll
        for (int mi = 0; mi < 4; ++mi)
            #pragma unroll
            for (int ni = 0; ni < 4; ++ni)
                acc[mi][ni] = __builtin_amdgcn_mfma_f32_16x16x32_bf16(
                    a1[mi], b1[ni], acc[mi][ni], 0, 0, 0);
    }

    // epilogue: D row = (lane>>4)*4 + reg, col = lane&15
    const int fr = lane & 15;
    const int fq = lane >> 4;
    #pragma unroll
    for (int mi = 0; mi < 4; ++mi) {
        #pragma unroll
        for (int ni = 0; ni < 4; ++ni) {
            int row = m0 + wm + mi * 16 + fq * 4;
            int col = n0 + wn + ni * 16 + fr;
            float bb = bias[col];
            #pragma unroll
            for (int r = 0; r < 4; ++r) {
                float v = acc[mi][ni][r] + bb;
                if (OUT_BF16)
                    ((unsigned short*)Cout)[(size_t)(row + r) * N + col] = f2bf(v);
                else
                    ((float*)Cout)[(size_t)(row + r) * N + col] = v;
            }
        }
    }
}

// ---------------- per-token head-axis attention, MFMA, row-major out ----------------
__global__ __launch_bounds__(256) void attn_mfma_kernel(
    const unsigned short* __restrict__ qkv,
    unsigned short* __restrict__ att) {
    __shared__ char smem[4 * 3584];
    const int w    = threadIdx.x >> 6;
    const int lane = threadIdx.x & 63;
    const int m    = lane & 15;
    const int q    = lane >> 4;
    const int row  = blockIdx.x * 4 + w;
    unsigned short* sV = (unsigned short*)(smem + w * 3584);        // [16][72] bf16
    float*          sP = (float*)(smem + w * 3584 + 2304);          // [16][20] fp32

    const unsigned short* src = qkv + (size_t)row * 3072;

    bf16x8 aq0 = *(const bf16x8*)(src + m * 64 + q * 8);
    bf16x8 aq1 = *(const bf16x8*)(src + m * 64 + 32 + q * 8);
    bf16x8 bk0 = *(const bf16x8*)(src + 1024 + m * 64 + q * 8);
    bf16x8 bk1 = *(const bf16x8*)(src + 1024 + m * 64 + 32 + q * 8);

    #pragma unroll
    for (int t = 0; t < 2; ++t) {
        int G = t * 64 + lane;
        int r = G >> 3, p = G & 7;
        *(uint4*)(sV + r * 72 + p * 8) = *(const uint4*)(src + 2048 + G * 8);
    }

    f32x4 s = {0.f, 0.f, 0.f, 0.f};
    s = __builtin_amdgcn_mfma_f32_16x16x32_bf16(aq0, bk0, s, 0, 0, 0);
    s = __builtin_amdgcn_mfma_f32_16x16x32_bf16(aq1, bk1, s, 0, 0, 0);

    #pragma unroll
    for (int r = 0; r < 4; ++r) {
        float t0 = s[r] * 0.125f;
        float mx = t0;
        mx = fmaxf(mx, __shfl_xor(mx, 1));
        mx = fmaxf(mx, __shfl_xor(mx, 2));
        mx = fmaxf(mx, __shfl_xor(mx, 4));
        mx = fmaxf(mx, __shfl_xor(mx, 8));
        float e = __expf(t0 - mx);
        float su = e;
        su += __shfl_xor(su, 1);
        su += __shfl_xor(su, 2);
        su += __shfl_xor(su, 4);
        su += __shfl_xor(su, 8);
        sP[(q * 4 + r) * 20 + m] = e / su;
    }
    __syncthreads();

    const float* pr = sP + m * 20 + (q & 1) * 8;
    float4 pf0 = *(const float4*)(pr);
    float4 pf1 = *(const float4*)(pr + 4);
    const bool act = (q < 2);
    union { unsigned short u[8]; bf16x8 b; } pa;
    pa.u[0] = act ? f2bf(pf0.x) : 0;
    pa.u[1] = act ? f2bf(pf0.y) : 0;
    pa.u[2] = act ? f2bf(pf0.z) : 0;
    pa.u[3] = act ? f2bf(pf0.w) : 0;
    pa.u[4] = act ? f2bf(pf1.x) : 0;
    pa.u[5] = act ? f2bf(pf1.y) : 0;
    pa.u[6] = act ? f2bf(pf1.z) : 0;
    pa.u[7] = act ? f2bf(pf1.w) : 0;

    const unsigned short* vb = sV + (q & 1) * 8 * 72;
    unsigned short* dst = att + (size_t)row * 1024;
    #pragma unroll
    for (int c4 = 0; c4 < 4; ++c4) {
        union { unsigned short u[8]; bf16x8 b; } vf;
        #pragma unroll
        for (int j = 0; j < 8; ++j) vf.u[j] = vb[j * 72 + c4 * 16 + m];
        f32x4 o = {0.f, 0.f, 0.f, 0.f};
        o = __builtin_amdgcn_mfma_f32_16x16x32_bf16(pa.b, vf.b, o, 0, 0, 0);
        unsigned short outv[4];
        #pragma unroll
        for (int r = 0; r < 4; ++r) outv[r] = f2bf(o[r]);
        // contiguous-ish stores: row h=q*4+r, cols c4*16+m -> use per-r scalar?
        // store 4 rows x 1 col each as packed u64 is not possible; instead write
        // to the 4 rows' same column: 4 scalar stores, cols coalesce across m.
        #pragma unroll
        for (int r = 0; r < 4; ++r)
            dst[(q * 4 + r) * 64 + c4 * 16 + m] = outv[r];
    }
}

extern "C" void kernel_launch(void* const* d_in, const int* in_sizes, int n_in,
                              void* d_out, int out_size, void* d_ws, size_t ws_size,
                              hipStream_t stream) {
    const float* x    = (const float*)d_in[0];
    const float* Wqkv = (const float*)d_in[1];
    const float* bqkv = (const float*)d_in[2];
    const float* Wout = (const float*)d_in[3];
    const float* bout = (const float*)d_in[4];
    float* out = (float*)d_out;

    // workspace: xp 32M | Wqkv_p 6M | Wout_p 2M | qkv 96M | attRM 32M = ~168 MB
    char* ws = (char*)d_ws;
    unsigned short* xp    = (unsigned short*)ws;                ws += (size_t)Mc * Kc * 2;
    unsigned short* Wqkp  = (unsigned short*)ws;                ws += (size_t)N1c * Kc * 2;
    unsigned short* Wop   = (unsigned short*)ws;                ws += (size_t)Cc * Kc * 2;
    unsigned short* qkv   = (unsigned short*)ws;                ws += (size_t)Mc * N1c * 2;
    unsigned short* attRM = (unsigned short*)ws;
    unsigned short* attP  = xp;   // alias: xp dead after GEMM1

    // 1) x -> packed bf16 fragments
    convert_x_packed<<<(Mc / 16) * KBc / 4, 256, 0, stream>>>(x, xp);
    // 2) weights -> packed bf16 fragments (transposed)
    transpose_convert_packed<<<dim3(N1c / 32, Kc / 32), dim3(32, 8), 0, stream>>>(Wqkv, Wqkp, Kc, N1c);
    transpose_convert_packed<<<dim3(Cc / 32, Kc / 32), dim3(32, 8), 0, stream>>>(Wout, Wop, Kc, Cc);
    // 3) qkv = x @ W_qkv + b_qkv   (bf16 row-major out); swizzled 1-D grid
    flat_gemm_kernel<true><<<(N1c / 128) * (Mc / 128), 256, 0, stream>>>(
        xp, Wqkp, bqkv, qkv, Mc, N1c, Kc, N1c / 128);
    // 4) head-axis attention per token (MFMA), row-major out
    attn_mfma_kernel<<<Mc / 4, 256, 0, stream>>>(qkv, attRM);
    // 4b) repack row-major -> packed fragments for GEMM2's A
    repack_bf16_packed<<<(Mc / 16) * KBc / 4, 256, 0, stream>>>(attRM, attP);
    // 5) out = att @ W_out + b_out (fp32 row-major out)
    flat_gemm_kernel<false><<<(Cc / 128) * (Mc / 128), 256, 0, stream>>>(
        attP, Wop, bout, out, Mc, Cc, Kc, Cc / 128);
}

// Round 5
// 295.880 us; speedup vs baseline: 1.2767x; 1.1248x over previous
//
#include <hip/hip_runtime.h>
#include <cstdint>
#include <cstddef>

// Problem constants
constexpr int Bc = 4;
constexpr int Tc = 4096;
constexpr int Cc = 1024;
constexpr int Hc = 16;
constexpr int Dc = 64;
constexpr int Mc = Bc * Tc;        // 16384 rows
constexpr int N1c = 3 * Cc;        // 3072
constexpr int Kc = Cc;             // 1024
constexpr int KBc = Kc / 32;       // 32 k-tiles

typedef __bf16 bf16x8 __attribute__((ext_vector_type(8)));
typedef float  f32x4  __attribute__((ext_vector_type(4)));
typedef __attribute__((address_space(1))) uint32_t gu32;
typedef __attribute__((address_space(3))) uint32_t lu32;

__device__ __forceinline__ float bf2f(unsigned short u) {
    return __uint_as_float(((unsigned)u) << 16);
}
__device__ __forceinline__ unsigned short f2bf(float f) {
    unsigned u = __float_as_uint(f);
    u += 0x7FFF + ((u >> 16) & 1);   // round-to-nearest-even (finite values)
    return (unsigned short)(u >> 16);
}

__device__ __forceinline__ void load_lds16(const void* g, void* l) {
    // wave-uniform LDS base + lane*16; per-lane global address
    __builtin_amdgcn_global_load_lds((gu32*)(uintptr_t)g, (lu32*)(uintptr_t)l, 16, 0, 0);
}

// ============ packed-fragment layout ============
// A 16(rows)x32(k) tile = 512 bf16 = 64 lanes x 8 elems, contiguous in lane order.
// lane = fq*16 + fr  (fr = row&15, fq = (k&31)>>3), elem j = k&7.
// tile index: (row>>4)*KB + (k>>5). Wave fragment load = tile_base + lane*16B
// -> one coalesced b128 (global) or one conflict-free ds_read_b128 (LDS).

// ---------------- x fp32 [M][K] -> packed bf16 fragments ----------------
__global__ void convert_x_packed(const float* __restrict__ x,
                                 unsigned short* __restrict__ Ap) {
    const int w = threadIdx.x >> 6, lane = threadIdx.x & 63;
    const int t = blockIdx.x * 4 + w;          // tile id = mb*KB + kb
    const int mb = t >> 5, kb = t & 31;
    const int r = lane >> 2, c = lane & 3;
    const float* src = x + (size_t)(mb * 16 + r) * Kc + kb * 32 + c * 8;
    float4 f0 = *(const float4*)src;
    float4 f1 = *(const float4*)(src + 4);
    unsigned short u[8];
    u[0] = f2bf(f0.x); u[1] = f2bf(f0.y); u[2] = f2bf(f0.z); u[3] = f2bf(f0.w);
    u[4] = f2bf(f1.x); u[5] = f2bf(f1.y); u[6] = f2bf(f1.z); u[7] = f2bf(f1.w);
    *(uint4*)(Ap + (size_t)t * 512 + (c * 16 + r) * 8) = *(uint4*)u;
}

// ---------------- W fp32 [K][N] -> packed bf16 fragments (transposed) ----------------
__global__ void transpose_convert_packed(const float* __restrict__ W,
                                         unsigned short* __restrict__ Bp,
                                         int K, int N) {
    __shared__ float tile[32][33];
    const int tx = threadIdx.x, ty = threadIdx.y;
    const int n0 = blockIdx.x * 32, k0 = blockIdx.y * 32;
    for (int i = ty; i < 32; i += 8)
        tile[i][tx] = W[(size_t)(k0 + i) * N + n0 + tx];
    __syncthreads();
    const int t = ty * 32 + tx;
    const int h = t >> 7, rr = t & 127, lane = rr >> 1, half = rr & 1;
    const int fq = lane >> 4, fn = lane & 15;
    unsigned short u[4];
    #pragma unroll
    for (int j = 0; j < 4; ++j)
        u[j] = f2bf(tile[fq * 8 + half * 4 + j][h * 16 + fn]);
    size_t tileIdx = (size_t)((n0 >> 4) + h) * (K >> 5) + (k0 >> 5);
    *(uint2*)(Bp + tileIdx * 512 + lane * 8 + half * 4) = *(uint2*)u;
}

// ---------------- LDS-staged bf16 MFMA GEMM on packed fragments ----------------
// m97 2-barrier K-loop, but LDS layout = packed fragment order:
//  - global_load_lds writes tile t to sX + t_local*512 (lane i -> +i*16B: DMA-native)
//  - ds_read_b128 fragment reads are linear in lane -> ZERO bank conflicts
// 128x128 block, 4 waves, 64x64 per wave = 4x4 MFMA(16x16x32).
// XCD swizzle: xcd = id%8 owns an M-stripe; A-stripe stays in its L2.
template <bool OUT_BF16>
__global__ __launch_bounds__(256, 4) void lds_gemm_kernel(
    const unsigned short* __restrict__ Ap,
    const unsigned short* __restrict__ Bp,
    const float* __restrict__ bias,
    void* __restrict__ Cout,
    int M, int N, int K, int NB) {
    __shared__ unsigned short sA[8 * 512];
    __shared__ unsigned short sB[8 * 512];
    const int KB = K >> 5;
    const int MB = M >> 7;
    const int id   = blockIdx.x;
    const int xcd  = id & 7;
    const int per  = id >> 3;
    const int MSTR = MB >> 3;
    const int byl  = per & 7;
    const int bx   = (per >> 3) % NB;
    const int pass = per / (8 * NB);
    const int by   = xcd * MSTR + pass * 8 + byl;

    const int w    = threadIdx.x >> 6;
    const int lane = threadIdx.x & 63;
    const int m0 = by * 128;
    const int n0 = bx * 128;
    const int wm = (w >> 1) * 64;
    const int wn = (w & 1) * 64;

    // DMA: wave w stages A tiles {w, w+4} and B tiles {w, w+4} of this k-step
    const unsigned short* gA0 = Ap + ((size_t)(by * 8 + w    ) * KB) * 512 + lane * 8;
    const unsigned short* gA1 = Ap + ((size_t)(by * 8 + w + 4) * KB) * 512 + lane * 8;
    const unsigned short* gB0 = Bp + ((size_t)(bx * 8 + w    ) * KB) * 512 + lane * 8;
    const unsigned short* gB1 = Bp + ((size_t)(bx * 8 + w + 4) * KB) * 512 + lane * 8;
    unsigned short* lA0 = sA + (w    ) * 512;
    unsigned short* lA1 = sA + (w + 4) * 512;
    unsigned short* lB0 = sB + (w    ) * 512;
    unsigned short* lB1 = sB + (w + 4) * 512;

    // fragment read pointers (linear in lane -> conflict-free ds_read_b128)
    const unsigned short* aP = sA + (wm >> 4) * 512 + lane * 8;
    const unsigned short* bP = sB + (wn >> 4) * 512 + lane * 8;

    const f32x4 zero4 = {0.f, 0.f, 0.f, 0.f};
    f32x4 acc[4][4];
    #pragma unroll
    for (int i = 0; i < 4; ++i)
        #pragma unroll
        for (int j = 0; j < 4; ++j) acc[i][j] = zero4;

    #pragma unroll 1
    for (int kb = 0; kb < KB; ++kb) {
        load_lds16(gA0, lA0);
        load_lds16(gA1, lA1);
        load_lds16(gB0, lB0);
        load_lds16(gB1, lB1);
        gA0 += 512; gA1 += 512; gB0 += 512; gB1 += 512;
        __syncthreads();   // drains DMA (vmcnt) + aligns waves

        bf16x8 af[4], bfr[4];
        #pragma unroll
        for (int mi = 0; mi < 4; ++mi) af[mi]  = *(const bf16x8*)(aP + mi * 512);
        #pragma unroll
        for (int ni = 0; ni < 4; ++ni) bfr[ni] = *(const bf16x8*)(bP + ni * 512);
        #pragma unroll
        for (int mi = 0; mi < 4; ++mi)
            #pragma unroll
            for (int ni = 0; ni < 4; ++ni)
                acc[mi][ni] = __builtin_amdgcn_mfma_f32_16x16x32_bf16(
                    af[mi], bfr[ni], acc[mi][ni], 0, 0, 0);
        __syncthreads();   // LDS consumed before next staging overwrites
    }

    // epilogue: D row = (lane>>4)*4 + reg, col = lane&15
    const int fr = lane & 15;
    const int fq = lane >> 4;
    #pragma unroll
    for (int mi = 0; mi < 4; ++mi) {
        #pragma unroll
        for (int ni = 0; ni < 4; ++ni) {
            int row = m0 + wm + mi * 16 + fq * 4;
            int col = n0 + wn + ni * 16 + fr;
            float bb = bias[col];
            #pragma unroll
            for (int r = 0; r < 4; ++r) {
                float v = acc[mi][ni][r] + bb;
                if (OUT_BF16)
                    ((unsigned short*)Cout)[(size_t)(row + r) * N + col] = f2bf(v);
                else
                    ((float*)Cout)[(size_t)(row + r) * N + col] = v;
            }
        }
    }
}

// ---------------- per-token head-axis attention, MFMA, packed-fragment out ----------------
// One wave per token; output written directly in packed-fragment layout so it
// feeds lds_gemm as A (no repack pass).
__global__ __launch_bounds__(256) void attn_mfma_kernel(
    const unsigned short* __restrict__ qkv,
    unsigned short* __restrict__ attP) {
    __shared__ char smem[4 * 3584];
    const int w    = threadIdx.x >> 6;
    const int lane = threadIdx.x & 63;
    const int m    = lane & 15;
    const int q    = lane >> 4;
    const int row  = blockIdx.x * 4 + w;
    unsigned short* sV = (unsigned short*)(smem + w * 3584);        // [16][72] bf16
    float*          sP = (float*)(smem + w * 3584 + 2304);          // [16][20] fp32

    const unsigned short* src = qkv + (size_t)row * 3072;

    bf16x8 aq0 = *(const bf16x8*)(src + m * 64 + q * 8);
    bf16x8 aq1 = *(const bf16x8*)(src + m * 64 + 32 + q * 8);
    bf16x8 bk0 = *(const bf16x8*)(src + 1024 + m * 64 + q * 8);
    bf16x8 bk1 = *(const bf16x8*)(src + 1024 + m * 64 + 32 + q * 8);

    #pragma unroll
    for (int t = 0; t < 2; ++t) {
        int G = t * 64 + lane;
        int r = G >> 3, p = G & 7;
        *(uint4*)(sV + r * 72 + p * 8) = *(const uint4*)(src + 2048 + G * 8);
    }

    f32x4 s = {0.f, 0.f, 0.f, 0.f};
    s = __builtin_amdgcn_mfma_f32_16x16x32_bf16(aq0, bk0, s, 0, 0, 0);
    s = __builtin_amdgcn_mfma_f32_16x16x32_bf16(aq1, bk1, s, 0, 0, 0);

    #pragma unroll
    for (int r = 0; r < 4; ++r) {
        float t0 = s[r] * 0.125f;
        float mx = t0;
        mx = fmaxf(mx, __shfl_xor(mx, 1));
        mx = fmaxf(mx, __shfl_xor(mx, 2));
        mx = fmaxf(mx, __shfl_xor(mx, 4));
        mx = fmaxf(mx, __shfl_xor(mx, 8));
        float e = __expf(t0 - mx);
        float su = e;
        su += __shfl_xor(su, 1);
        su += __shfl_xor(su, 2);
        su += __shfl_xor(su, 4);
        su += __shfl_xor(su, 8);
        sP[(q * 4 + r) * 20 + m] = e / su;
    }
    __syncthreads();

    const float* pr = sP + m * 20 + (q & 1) * 8;
    float4 pf0 = *(const float4*)(pr);
    float4 pf1 = *(const float4*)(pr + 4);
    const bool act = (q < 2);
    union { unsigned short u[8]; bf16x8 b; } pa;
    pa.u[0] = act ? f2bf(pf0.x) : 0;
    pa.u[1] = act ? f2bf(pf0.y) : 0;
    pa.u[2] = act ? f2bf(pf0.z) : 0;
    pa.u[3] = act ? f2bf(pf0.w) : 0;
    pa.u[4] = act ? f2bf(pf1.x) : 0;
    pa.u[5] = act ? f2bf(pf1.y) : 0;
    pa.u[6] = act ? f2bf(pf1.z) : 0;
    pa.u[7] = act ? f2bf(pf1.w) : 0;

    const unsigned short* vb = sV + (q & 1) * 8 * 72;
    const size_t tileBase = (size_t)(row >> 4) * 32 * 512;   // token's m-block row (KB=32)
    const int fr_tok = row & 15;
    #pragma unroll
    for (int c4 = 0; c4 < 4; ++c4) {
        union { unsigned short u[8]; bf16x8 b; } vf;
        #pragma unroll
        for (int j = 0; j < 8; ++j) vf.u[j] = vb[j * 72 + c4 * 16 + m];
        f32x4 o = {0.f, 0.f, 0.f, 0.f};
        o = __builtin_amdgcn_mfma_f32_16x16x32_bf16(pa.b, vf.b, o, 0, 0, 0);
        #pragma unroll
        for (int r = 0; r < 4; ++r) {
            int col = (q * 4 + r) * 64 + c4 * 16 + m;        // k index in [0,1024)
            size_t off = tileBase + (size_t)(col >> 5) * 512
                       + (((col >> 3) & 3) * 16 + fr_tok) * 8 + (col & 7);
            attP[off] = f2bf(o[r]);
        }
    }
}

extern "C" void kernel_launch(void* const* d_in, const int* in_sizes, int n_in,
                              void* d_out, int out_size, void* d_ws, size_t ws_size,
                              hipStream_t stream) {
    const float* x    = (const float*)d_in[0];
    const float* Wqkv = (const float*)d_in[1];
    const float* bqkv = (const float*)d_in[2];
    const float* Wout = (const float*)d_in[3];
    const float* bout = (const float*)d_in[4];
    float* out = (float*)d_out;

    // workspace: xp 32M | Wqkv_p 6M | Wout_p 2M | qkv 96M = ~136 MB
    char* ws = (char*)d_ws;
    unsigned short* xp   = (unsigned short*)ws;                 ws += (size_t)Mc * Kc * 2;
    unsigned short* Wqkp = (unsigned short*)ws;                 ws += (size_t)N1c * Kc * 2;
    unsigned short* Wop  = (unsigned short*)ws;                 ws += (size_t)Cc * Kc * 2;
    unsigned short* qkv  = (unsigned short*)ws;
    unsigned short* attP = xp;   // alias: xp dead after GEMM1

    // 1) x -> packed bf16 fragments
    convert_x_packed<<<(Mc / 16) * KBc / 4, 256, 0, stream>>>(x, xp);
    // 2) weights -> packed bf16 fragments (transposed)
    transpose_convert_packed<<<dim3(N1c / 32, Kc / 32), dim3(32, 8), 0, stream>>>(Wqkv, Wqkp, Kc, N1c);
    transpose_convert_packed<<<dim3(Cc / 32, Kc / 32), dim3(32, 8), 0, stream>>>(Wout, Wop, Kc, Cc);
    // 3) qkv = x @ W_qkv + b_qkv   (bf16 row-major out)
    lds_gemm_kernel<true><<<(N1c / 128) * (Mc / 128), 256, 0, stream>>>(
        xp, Wqkp, bqkv, qkv, Mc, N1c, Kc, N1c / 128);
    // 4) head-axis attention per token (MFMA), writes packed-fragment A
    attn_mfma_kernel<<<Mc / 4, 256, 0, stream>>>(qkv, attP);
    // 5) out = att @ W_out + b_out (fp32 row-major out)
    lds_gemm_kernel<false><<<(Cc / 128) * (Mc / 128), 256, 0, stream>>>(
        attP, Wop, bout, out, Mc, Cc, Kc, Cc / 128);
}